// Round 14
// baseline (275.718 us; speedup 1.0000x reference)
//
#include <hip/hip_runtime.h>
#include <hip/hip_fp16.h>
#include <math.h>

#define N_NODES 100000
#define N_EDGES 3200000
#define GRID_N 391        // ceil(100000/256)
#define GRID_G 6250       // ceil(100000/16)
#define NSB 782           // ceil(100000/128) super-buckets
#define SB_NODES 128
#define SBCAP 5120        // mean 4096, std 64 -> +16 sigma
#define E_BLK 12800       // edges per k_part block (250*12800 == N_EDGES exactly)
#define CH_E 6400         // local-sort chunk (2 chunks/block keeps LDS at 38 KB)
#define PART_BLOCKS 250
#define PART_THREADS 1024
#define GRID_DEC 12500    // 3.2M / 256, 1 edge per thread

// ---------------- ws float layout (element offsets) ----------------
#define OFF_DINV 0
#define OFF_C    100016
#define OFF_ZS16 200032      // 100000 x 16 halfs (dinv-scaled z)
#define OFF_T16  1000048     // 100000 x 16 halfs
#define OFF_U    1800064     // 100000 x 16 fp32
#define OFF_YT   3400080     // 100000 x 32B (16 fp16), 16B-aligned
#define OFF_ST   4200080     // 100000 x 8B (4 fp16: r1,r2,r3,r4)
#define OFF_PR   6604720
#define OFF_PB   6604736
#define OFF_ABG  6604752     // beta, gamma/2, lam+, lam-, k1, k2
#define OFF_L    6604768     // 16x16 Cholesky factor of G
#define FLOAT_TOTAL 6605024
// int region (elements into (int*)(ws + FLOAT_TOTAL))
#define IOFF_GCUR 0
#define IOFF_BEG  1024
#define IOFF_CNT  101024
#define IOFF_BUF  201024     // 782*5120
#define IOFF_CSR  4204864    // 782*5120
// ws total ~59 MB

// ---- half helpers ----
__device__ inline float4 h4_to_f4(uint2 v) {
    __half2 a = *reinterpret_cast<__half2*>(&v.x);
    __half2 b = *reinterpret_cast<__half2*>(&v.y);
    float2 fa = __half22float2(a), fb = __half22float2(b);
    return make_float4(fa.x, fa.y, fb.x, fb.y);
}
__device__ inline uint2 f4_to_h4(float4 f) {
    uint2 r;
    __half2 a = __floats2half2_rn(f.x, f.y);
    __half2 b = __floats2half2_rn(f.z, f.w);
    r.x = *reinterpret_cast<unsigned*>(&a);
    r.y = *reinterpret_cast<unsigned*>(&b);
    return r;
}
__device__ inline float4 pack_h8(float4 a, float4 b) {
    float4 r;
    __half2* p = reinterpret_cast<__half2*>(&r);
    p[0] = __floats2half2_rn(a.x, a.y);
    p[1] = __floats2half2_rn(a.z, a.w);
    p[2] = __floats2half2_rn(b.x, b.y);
    p[3] = __floats2half2_rn(b.z, b.w);
    return r;
}
__device__ inline uint4 f8_to_h8(float4 a, float4 b) {
    uint4 r;
    __half2 h0 = __floats2half2_rn(a.x, a.y);
    __half2 h1 = __floats2half2_rn(a.z, a.w);
    __half2 h2 = __floats2half2_rn(b.x, b.y);
    __half2 h3 = __floats2half2_rn(b.z, b.w);
    r.x = *reinterpret_cast<unsigned*>(&h0);
    r.y = *reinterpret_cast<unsigned*>(&h1);
    r.z = *reinterpret_cast<unsigned*>(&h2);
    r.w = *reinterpret_cast<unsigned*>(&h3);
    return r;
}
__device__ inline unsigned h2bits(float a, float b) {
    __half2 h = __floats2half2_rn(a, b);
    return *reinterpret_cast<unsigned*>(&h);
}
__device__ inline float2 bits2f2(unsigned v) {
    __half2 h = *reinterpret_cast<__half2*>(&v);
    return __half22float2(h);
}
__device__ inline float hdot8f(float4 a, float4 b) {
    const __half2* pa = reinterpret_cast<const __half2*>(&a);
    const __half2* pb = reinterpret_cast<const __half2*>(&b);
    float s = 0.0f;
    #pragma unroll
    for (int i = 0; i < 4; i++) {
        float2 fa = __half22float2(pa[i]);
        float2 fb = __half22float2(pb[i]);
        s += fa.x * fb.x + fa.y * fb.y;
    }
    return s;
}
// accumulate 8 halfs (uint4) into two float4 accumulators
__device__ inline void acc8(float4& lo, float4& hi, uint4 v) {
    float2 p0 = __half22float2(*reinterpret_cast<__half2*>(&v.x));
    float2 p1 = __half22float2(*reinterpret_cast<__half2*>(&v.y));
    float2 p2 = __half22float2(*reinterpret_cast<__half2*>(&v.z));
    float2 p3 = __half22float2(*reinterpret_cast<__half2*>(&v.w));
    lo.x += p0.x; lo.y += p0.y; lo.z += p1.x; lo.w += p1.y;
    hi.x += p2.x; hi.y += p2.y; hi.z += p3.x; hi.w += p3.y;
}

// ---- shared-memory unions for the merged part+consts kernel ----
struct ConstsSh {
    float sW1t[16 * 256];
    float sM[16 * 257];
    float sb1[256];
    float sb2[256];
    float sR[256];
    float sG[256];
    float sLf[256];
};
// local counting-sort staging (per 6400-edge chunk): 38.1 KB total
struct PartSh {
    int h2[2][NSB];      // 6.3 KB
    int pref[NSB + 1];   // 3.1 KB  (scan -> bucket starts -> cursors -> ends)
    int gbase[NSB];      // 3.1 KB
    int pay[CH_E];       // 25.6 KB (chunk's edges, sorted by super-bucket)
};

// ---- phase A: block-local counting sort (2 chunks) -> coalesced run writes.
//      Extra block (blockIdx == PART_BLOCKS) computes weight-constants. ----
__global__ void __launch_bounds__(PART_THREADS)
k_part(const int* __restrict__ src, const int* __restrict__ dst,
       int* __restrict__ gcur, int* __restrict__ buf,
       const float* __restrict__ W1, const float* __restrict__ b1,
       const float* __restrict__ W2, const float* __restrict__ b2,
       float* __restrict__ ws) {
    __shared__ union { ConstsSh c; PartSh p; } sh;
    int t = threadIdx.x;

    if (blockIdx.x == PART_BLOCKS) {
        bool act = t < 256;
        if (act) {
            #pragma unroll
            for (int r = 0; r < 16; r++)
                sh.c.sW1t[t * 16 + r] = W1[r * 256 + t];
            sh.c.sb1[t] = b1[t];
            sh.c.sb2[t] = b2[t];
        }
        __syncthreads();
        if (act) {
            float acc[16];
            #pragma unroll
            for (int i = 0; i < 16; i++) acc[i] = 0.0f;
            float raccv = 0.0f;
            for (int kk = 0; kk < 256; kk += 8) {
                float w2v[8];
                #pragma unroll
                for (int u = 0; u < 8; u++)
                    w2v[u] = W2[(kk + u) * 256 + t];
                #pragma unroll
                for (int u = 0; u < 8; u++) {
                    #pragma unroll
                    for (int i = 0; i < 16; i++)
                        acc[i] += sh.c.sW1t[(kk + u) * 16 + i] * w2v[u];
                    raccv += sh.c.sb1[kk + u] * w2v[u];
                }
            }
            #pragma unroll
            for (int i = 0; i < 16; i++) sh.c.sM[i * 257 + t] = acc[i];
            sh.c.sR[t] = raccv;
        }
        __syncthreads();
        if (act) {
            int i = t >> 4, j = t & 15;
            float gg = 0.0f;
            for (int tt = 0; tt < 256; tt++)
                gg += sh.c.sM[i * 257 + tt] * sh.c.sM[j * 257 + tt];
            sh.c.sG[t] = gg;
        }
        if (t < 16) {
            float a = 0.0f, b = 0.0f;
            for (int tt = 0; tt < 256; tt++) {
                a += sh.c.sM[t * 257 + tt] * sh.c.sR[tt];
                b += sh.c.sM[t * 257 + tt] * sh.c.sb2[tt];
            }
            ws[OFF_PR + t] = a;
            ws[OFF_PB + t] = b;
        }
        if (t == 0) {
            float al = 0.0f, be = 0.0f, ga = 0.0f;
            for (int tt = 0; tt < 256; tt++) {
                al += sh.c.sR[tt] * sh.c.sR[tt];
                be += sh.c.sR[tt] * sh.c.sb2[tt];
                ga += sh.c.sb2[tt] * sh.c.sb2[tt];
            }
            float disc = sqrtf(al * al + 4.0f);
            float lp = 0.5f * (al + disc);
            float lm = 0.5f * (al - disc);
            float k1 = sqrtf(lp / (lp * lp + 1.0f));
            float k2 = sqrtf(-lm / (lm * lm + 1.0f));
            ws[OFF_ABG + 0] = be;
            ws[OFF_ABG + 1] = 0.5f * ga;
            ws[OFF_ABG + 2] = lp;
            ws[OFF_ABG + 3] = lm;
            ws[OFF_ABG + 4] = k1;
            ws[OFF_ABG + 5] = k2;
        }
        __syncthreads();
        if (act) sh.c.sLf[t] = 0.0f;
        __syncthreads();
        // parallel Cholesky: 16 steps, column-parallel
        for (int j = 0; j < 16; j++) {
            if (t == j) {
                float s = sh.c.sG[j * 16 + j];
                for (int k = 0; k < j; k++)
                    s -= sh.c.sLf[j * 16 + k] * sh.c.sLf[j * 16 + k];
                sh.c.sLf[j * 16 + j] = sqrtf(fmaxf(s, 1e-20f));
            }
            __syncthreads();
            if (t > j && t < 16) {
                float s = sh.c.sG[t * 16 + j];
                for (int k = 0; k < j; k++)
                    s -= sh.c.sLf[t * 16 + k] * sh.c.sLf[j * 16 + k];
                sh.c.sLf[t * 16 + j] = s / sh.c.sLf[j * 16 + j];
            }
            __syncthreads();
        }
        if (act) ws[OFF_L + t] = sh.c.sLf[t];
        return;
    }

    // ===== binning path: local counting sort, 2 chunks of 6400 edges =====
    int cp = t >> 9;   // 2 hist copies
    for (int chunk = 0; chunk < 2; chunk++) {
        int cbase = blockIdx.x * E_BLK + chunk * CH_E;
        for (int i = t; i < 2 * NSB; i += PART_THREADS) ((int*)sh.p.h2)[i] = 0;
        __syncthreads();
        // pass 1: count
        for (int i = t; i < CH_E; i += PART_THREADS) {
            int e = cbase + i;
            if (e < N_EDGES)
                atomicAdd(&sh.p.h2[cp][__builtin_nontemporal_load(dst + e) >> 7], 1);
        }
        __syncthreads();
        // prefix: pref[0]=0, pref[i+1]=cnt_i, inclusive scan -> bucket starts
        if (t == 0) sh.p.pref[0] = 0;
        if (t < NSB) sh.p.pref[t + 1] = sh.p.h2[0][t] + sh.p.h2[1][t];
        __syncthreads();
        for (int off = 1; off <= NSB; off <<= 1) {
            int v = 0;
            if (t <= NSB && t >= off) v = sh.p.pref[t - off];
            __syncthreads();
            if (t <= NSB) sh.p.pref[t] += v;
            __syncthreads();
        }
        // pass 2: scatter into LDS, sorted by sb (pref[sb] = running cursor)
        for (int i = t; i < CH_E; i += PART_THREADS) {
            int e = cbase + i;
            if (e >= N_EDGES) continue;
            int d = __builtin_nontemporal_load(dst + e);
            int s = __builtin_nontemporal_load(src + e);
            int sb = d >> 7;
            int pos = atomicAdd(&sh.p.pref[sb], 1);
            sh.p.pay[pos] = s | ((d & 127) << 17);
        }
        __syncthreads();
        // pass 3: reserve one contiguous global run per bucket.
        if (t < NSB) {
            int end   = sh.p.pref[t];
            int start = (t == 0) ? 0 : sh.p.pref[t - 1];
            int cnt   = end - start;
            sh.p.gbase[t] = (cnt > 0) ? atomicAdd(&gcur[t], cnt) : 0;
        }
        __syncthreads();
        int tot = sh.p.pref[NSB];   // untouched by pass 2 (sb < NSB)
        // pass 4: coalesced copy-out; consecutive k in a bucket -> consecutive addrs
        for (int k = t; k < tot; k += PART_THREADS) {
            int lo = 0, hi = NSB - 1;          // smallest sb with end(sb) > k
            while (lo < hi) {
                int mid = (lo + hi) >> 1;
                if (sh.p.pref[mid] > k) hi = mid; else lo = mid + 1;
            }
            int sb  = lo;
            int ofs = k - ((sb == 0) ? 0 : sh.p.pref[sb - 1]);
            int p   = sh.p.gbase[sb] + ofs;
            if (p < SBCAP) buf[sb * SBCAP + p] = sh.p.pay[k];
        }
        __syncthreads();   // pay/pref/gbase reads done before next chunk reuses
    }
}

// ---- phase B: per-SB counting sort -> exact CSR, fused dinv + zs16 ----
__global__ void k_sort(const float* __restrict__ z, const int* __restrict__ gcur,
                       const int* __restrict__ buf, int* __restrict__ csr,
                       int* __restrict__ begA, int* __restrict__ cntA,
                       float* __restrict__ ws) {
    __shared__ int pay[SBCAP];
    __shared__ int h[SB_NODES + 1];
    __shared__ int lcur[SB_NODES];
    __shared__ float sdv[SB_NODES];
    int sb = blockIdx.x, t = threadIdx.x;
    int n = gcur[sb];
    if (n > SBCAP) n = SBCAP;
    for (int i = t; i < n; i += 256) pay[i] = buf[sb * SBCAP + i];
    if (t <= SB_NODES) h[t] = 0;
    __syncthreads();
    for (int i = t; i < n; i += 256) atomicAdd(&h[(pay[i] >> 17) + 1], 1);
    __syncthreads();
    int mydeg = 0;
    if (t < SB_NODES) { mydeg = h[t + 1]; h[t + 1] = (mydeg + 3) & ~3; }
    __syncthreads();
    for (int off = 1; off <= SB_NODES; off <<= 1) {
        int v = 0;
        if (t <= SB_NODES && t >= off) v = h[t - off];
        __syncthreads();
        if (t <= SB_NODES) h[t] += v;
        __syncthreads();
    }
    int n0 = sb * SB_NODES;
    if (t < SB_NODES) {
        lcur[t] = h[t];
        float dv = rsqrtf((float)(mydeg + 1));
        sdv[t] = dv;
        if (n0 + t < N_NODES) {
            cntA[n0 + t] = mydeg;
            begA[n0 + t] = sb * SBCAP + h[t];
            ws[OFF_DINV + n0 + t] = dv;
        }
    }
    __syncthreads();
    {
        int nl = t >> 1, half = t & 1;
        int node = n0 + nl;
        if (node < N_NODES) {
            const float4* zr = (const float4*)(z + (size_t)node * 16) + 2 * half;
            float dv = sdv[nl];
            float4 a = zr[0], b = zr[1];
            a = make_float4(a.x * dv, a.y * dv, a.z * dv, a.w * dv);
            b = make_float4(b.x * dv, b.y * dv, b.z * dv, b.w * dv);
            ((float4*)((__half*)(ws + OFF_ZS16) + (size_t)node * 16))[half] = pack_h8(a, b);
        }
    }
    for (int i = t; i < n; i += 256) {
        int p = pay[i];
        int dl = p >> 17;
        int pos = atomicAdd(&lcur[dl], 1);
        if (pos < SBCAP) csr[sb * SBCAP + pos] = p & 0x1FFFF;
    }
}

// ---- pass 1 (half-row, 4-deep): h = lane&1 owns 16B of the row, el = lane>>1
//      owns edge slots; 4 gathers in flight per iteration (one iteration covers
//      the average node's 32 edges). ~45 VGPR, no spill. ----
__global__ void k_gather1(const int* __restrict__ cntA, const int* __restrict__ begA,
                          const int* __restrict__ csr, float* __restrict__ ws) {
    int tid = threadIdx.x;
    int lane16 = tid & 15;
    int g = tid >> 4;
    int h = lane16 & 1;      // half of row (0: dims 0-7, 1: dims 8-15)
    int el = lane16 >> 1;    // edge slot 0..7
    int d = blockIdx.x * 16 + g;
    if (d >= N_NODES) return;
    const float* dinv = ws + OFF_DINV;
    const __half* zs = (const __half*)(ws + OFF_ZS16);
    float dd = dinv[d];
    float dv2 = dd * dd;
    int deg = cntA[d];
    int beg = begA[d];
    float4 a0 = make_float4(0.f, 0.f, 0.f, 0.f), a1 = a0;
    float csum = 0.0f;
    int j = el;
    for (; j + 24 < deg; j += 32) {
        int s0 = csr[beg + j];
        int s1 = csr[beg + j + 8];
        int s2 = csr[beg + j + 16];
        int s3 = csr[beg + j + 24];
        uint4 p0 = *(const uint4*)(zs + (size_t)s0 * 16 + h * 8);
        uint4 p1 = *(const uint4*)(zs + (size_t)s1 * 16 + h * 8);
        uint4 p2 = *(const uint4*)(zs + (size_t)s2 * 16 + h * 8);
        uint4 p3 = *(const uint4*)(zs + (size_t)s3 * 16 + h * 8);
        float dv = 0.0f;
        if (h == 0) dv = (dinv[s0] + dinv[s1]) + (dinv[s2] + dinv[s3]);
        __builtin_amdgcn_sched_barrier(0);   // keep all 4 gathers in flight
        acc8(a0, a1, p0);
        acc8(a0, a1, p1);
        acc8(a0, a1, p2);
        acc8(a0, a1, p3);
        csum += dv;
    }
    for (; j + 8 < deg; j += 16) {
        int s0 = csr[beg + j];
        int s1 = csr[beg + j + 8];
        uint4 p0 = *(const uint4*)(zs + (size_t)s0 * 16 + h * 8);
        uint4 p1 = *(const uint4*)(zs + (size_t)s1 * 16 + h * 8);
        float dv = 0.0f;
        if (h == 0) dv = dinv[s0] + dinv[s1];
        __builtin_amdgcn_sched_barrier(0);
        acc8(a0, a1, p0);
        acc8(a0, a1, p1);
        csum += dv;
    }
    if (j < deg) {
        int s0 = csr[beg + j];
        uint4 p0 = *(const uint4*)(zs + (size_t)s0 * 16 + h * 8);
        float dv = (h == 0) ? dinv[s0] : 0.0f;
        __builtin_amdgcn_sched_barrier(0);
        acc8(a0, a1, p0);
        csum += dv;
    }
    // reduce over the 8 edge slots (xor 2,4,8; h preserved)
    #pragma unroll
    for (int m = 2; m <= 8; m <<= 1) {
        a0.x += __shfl_xor(a0.x, m, 64); a0.y += __shfl_xor(a0.y, m, 64);
        a0.z += __shfl_xor(a0.z, m, 64); a0.w += __shfl_xor(a0.w, m, 64);
        a1.x += __shfl_xor(a1.x, m, 64); a1.y += __shfl_xor(a1.y, m, 64);
        a1.z += __shfl_xor(a1.z, m, 64); a1.w += __shfl_xor(a1.w, m, 64);
        csum += __shfl_xor(csum, m, 64);
    }
    if (el == 0) {
        // add own row half, scale, write this lane's 16B chunk
        uint4 zq = *(const uint4*)(zs + (size_t)d * 16 + h * 8);
        float4 z0 = make_float4(0.f, 0.f, 0.f, 0.f), z1 = z0;
        acc8(z0, z1, zq);
        float4 o0 = make_float4(dv2 * (a0.x + z0.x), dv2 * (a0.y + z0.y),
                                dv2 * (a0.z + z0.z), dv2 * (a0.w + z0.w));
        float4 o1 = make_float4(dv2 * (a1.x + z1.x), dv2 * (a1.y + z1.y),
                                dv2 * (a1.z + z1.z), dv2 * (a1.w + z1.w));
        ((uint4*)((__half*)(ws + OFF_T16) + (size_t)d * 16))[h] = f8_to_h8(o0, o1);
        if (h == 0) (ws + OFF_C)[d] = dd * csum + dv2;
    }
}

// ---- pass 2 (half-row, 4-deep): u = dd * (sum t16[s] + t16[d]) -> U fp32 ----
__global__ void k_gather2(const int* __restrict__ cntA, const int* __restrict__ begA,
                          const int* __restrict__ csr, float* __restrict__ ws) {
    int tid = threadIdx.x;
    int lane16 = tid & 15;
    int g = tid >> 4;
    int h = lane16 & 1;
    int el = lane16 >> 1;
    int d = blockIdx.x * 16 + g;
    if (d >= N_NODES) return;
    const float* dinv = ws + OFF_DINV;
    const __half* t16 = (const __half*)(ws + OFF_T16);
    float dd = dinv[d];
    int deg = cntA[d];
    int beg = begA[d];
    float4 a0 = make_float4(0.f, 0.f, 0.f, 0.f), a1 = a0;
    int j = el;
    for (; j + 24 < deg; j += 32) {
        int s0 = csr[beg + j];
        int s1 = csr[beg + j + 8];
        int s2 = csr[beg + j + 16];
        int s3 = csr[beg + j + 24];
        uint4 p0 = *(const uint4*)(t16 + (size_t)s0 * 16 + h * 8);
        uint4 p1 = *(const uint4*)(t16 + (size_t)s1 * 16 + h * 8);
        uint4 p2 = *(const uint4*)(t16 + (size_t)s2 * 16 + h * 8);
        uint4 p3 = *(const uint4*)(t16 + (size_t)s3 * 16 + h * 8);
        __builtin_amdgcn_sched_barrier(0);   // keep all 4 gathers in flight
        acc8(a0, a1, p0);
        acc8(a0, a1, p1);
        acc8(a0, a1, p2);
        acc8(a0, a1, p3);
    }
    for (; j + 8 < deg; j += 16) {
        int s0 = csr[beg + j];
        int s1 = csr[beg + j + 8];
        uint4 p0 = *(const uint4*)(t16 + (size_t)s0 * 16 + h * 8);
        uint4 p1 = *(const uint4*)(t16 + (size_t)s1 * 16 + h * 8);
        __builtin_amdgcn_sched_barrier(0);
        acc8(a0, a1, p0);
        acc8(a0, a1, p1);
    }
    if (j < deg) {
        int s0 = csr[beg + j];
        uint4 p0 = *(const uint4*)(t16 + (size_t)s0 * 16 + h * 8);
        __builtin_amdgcn_sched_barrier(0);
        acc8(a0, a1, p0);
    }
    #pragma unroll
    for (int m = 2; m <= 8; m <<= 1) {
        a0.x += __shfl_xor(a0.x, m, 64); a0.y += __shfl_xor(a0.y, m, 64);
        a0.z += __shfl_xor(a0.z, m, 64); a0.w += __shfl_xor(a0.w, m, 64);
        a1.x += __shfl_xor(a1.x, m, 64); a1.y += __shfl_xor(a1.y, m, 64);
        a1.z += __shfl_xor(a1.z, m, 64); a1.w += __shfl_xor(a1.w, m, 64);
    }
    if (el == 0) {
        uint4 tq = *(const uint4*)(t16 + (size_t)d * 16 + h * 8);
        float4 z0 = make_float4(0.f, 0.f, 0.f, 0.f), z1 = z0;
        acc8(z0, z1, tq);
        float4 o0 = make_float4(dd * (a0.x + z0.x), dd * (a0.y + z0.y),
                                dd * (a0.z + z0.z), dd * (a0.w + z0.w));
        float4 o1 = make_float4(dd * (a1.x + z1.x), dd * (a1.y + z1.y),
                                dd * (a1.z + z1.z), dd * (a1.w + z1.w));
        float4* urow = (float4*)(ws + OFF_U + (size_t)d * 16);
        urow[h * 2]     = o0;
        urow[h * 2 + 1] = o1;
    }
}

// ---- per node (separate, full-width streaming): ytab + stab ----
__global__ void k_pack(float* __restrict__ ws) {
    __shared__ float sL[256];
    __shared__ float spr[16];
    __shared__ float spb[16];
    __shared__ float sprm[8];
    int tid = threadIdx.x;
    sL[tid] = ws[OFF_L + tid];
    if (tid < 16) { spr[tid] = ws[OFF_PR + tid]; spb[tid] = ws[OFF_PB + tid]; }
    if (tid < 8) sprm[tid] = ws[OFF_ABG + tid];
    __syncthreads();
    int i = blockIdx.x * blockDim.x + tid;
    if (i >= N_NODES) return;
    const float* u = ws + OFF_U;
    const float* c = ws + OFF_C;
    float ur[16];
    const float4* urow = (const float4*)(u + (size_t)i * 16);
    #pragma unroll
    for (int m = 0; m < 4; m++) {
        float4 a = urow[m];
        ur[4 * m + 0] = a.x; ur[4 * m + 1] = a.y;
        ur[4 * m + 2] = a.z; ur[4 * m + 3] = a.w;
    }
    float A = 0.0f, B = 0.0f;
    #pragma unroll
    for (int kk = 0; kk < 16; kk++) { A += ur[kk] * spr[kk]; B += ur[kk] * spb[kk]; }
    float y[16];
    #pragma unroll
    for (int j = 0; j < 16; j++) {
        float accv = 0.0f;
        #pragma unroll
        for (int kk = 0; kk < 16; kk++) accv += ur[kk] * sL[kk * 16 + j];
        y[j] = accv;
    }
    float beta = sprm[0], gh = sprm[1], lp = sprm[2], lm = sprm[3];
    float k1 = sprm[4], k2 = sprm[5];
    float ci = c[i];
    float Ap = A + beta;
    float Bp = B + gh;
    float r1 = k1 * (lp * ci + Ap);
    float r2 = k2 * (lm * ci + Ap);
    const float inv_s2 = 0.70710678118654752f;
    float r3 = (Bp + 1.0f) * inv_s2;
    float r4 = (Bp - 1.0f) * inv_s2;
    float4* yt = (float4*)(ws + OFF_YT);
    yt[2 * i]     = pack_h8(make_float4(y[0], y[1], y[2], y[3]),
                            make_float4(y[4], y[5], y[6], y[7]));
    yt[2 * i + 1] = pack_h8(make_float4(y[8], y[9], y[10], y[11]),
                            make_float4(y[12], y[13], y[14], y[15]));
    ((uint2*)(ws + OFF_ST))[i] = make_uint2(h2bits(r1, r2), h2bits(r3, r4));
}

// ---- decoder, 1 edge per thread (best measured: 65.7 µs) ----
__global__ void k_decode(const int* __restrict__ src, const int* __restrict__ dst,
                         const float* __restrict__ ws, float* __restrict__ out) {
    int e = blockIdx.x * 256 + threadIdx.x;   // GRID_DEC*256 == N_EDGES exactly
    const float4* yt = (const float4*)(ws + OFF_YT);
    const uint2*  st = (const uint2*)(ws + OFF_ST);
    int s = __builtin_nontemporal_load(src + e);
    int d = __builtin_nontemporal_load(dst + e);
    float4 sy0 = yt[2 * (size_t)s];
    float4 sy1 = yt[2 * (size_t)s + 1];
    float4 dy0 = yt[2 * (size_t)d];
    float4 dy1 = yt[2 * (size_t)d + 1];
    uint2  ssc = st[s];
    uint2  dsc = st[d];
    __builtin_amdgcn_sched_barrier(0);   // all 6 gathers stay in flight
    float v = hdot8f(sy0, dy0) + hdot8f(sy1, dy1);
    float2 ra = bits2f2(ssc.x), rb = bits2f2(dsc.x);
    float2 rc = bits2f2(ssc.y), rd = bits2f2(dsc.y);
    v += ra.x * rb.x - ra.y * rb.y + rc.x * rd.x - rc.y * rd.y;
    __builtin_nontemporal_store(1.0f / (1.0f + expf(-v)), out + e);
}

extern "C" void kernel_launch(void* const* d_in, const int* in_sizes, int n_in,
                              void* d_out, int out_size, void* d_ws, size_t ws_size,
                              hipStream_t stream) {
    const float* z  = (const float*)d_in[0];
    const int*   ei = (const int*)d_in[1];
    const float* W1 = (const float*)d_in[2];
    const float* b1 = (const float*)d_in[3];
    const float* W2 = (const float*)d_in[4];
    const float* b2 = (const float*)d_in[5];
    float* out = (float*)d_out;
    float* ws  = (float*)d_ws;
    int*   wi  = (int*)(ws + FLOAT_TOTAL);

    const int* src = ei;
    const int* dst = ei + N_EDGES;

    int* gcur = wi + IOFF_GCUR;
    int* begA = wi + IOFF_BEG;
    int* cntA = wi + IOFF_CNT;
    int* buf  = wi + IOFF_BUF;
    int* csr  = wi + IOFF_CSR;

    hipMemsetAsync(gcur, 0, 1024 * sizeof(int), stream);
    k_part    <<<PART_BLOCKS + 1, PART_THREADS, 0, stream>>>(src, dst, gcur, buf,
                                                             W1, b1, W2, b2, ws);
    k_sort    <<<NSB, 256, 0, stream>>>(z, gcur, buf, csr, begA, cntA, ws);
    k_gather1 <<<GRID_G, 256, 0, stream>>>(cntA, begA, csr, ws);
    k_gather2 <<<GRID_G, 256, 0, stream>>>(cntA, begA, csr, ws);
    k_pack    <<<GRID_N, 256, 0, stream>>>(ws);
    k_decode  <<<GRID_DEC, 256, 0, stream>>>(src, dst, ws, out);
}